// Round 22
// baseline (61.325 us; speedup 1.0000x reference)
//
#include <hip/hip_runtime.h>

typedef __bf16 bf16x8 __attribute__((ext_vector_type(8)));
typedef float f32x4 __attribute__((ext_vector_type(4)));
typedef unsigned short u16x4 __attribute__((ext_vector_type(4)));
typedef unsigned short u16x8 __attribute__((ext_vector_type(8)));
typedef unsigned int u32x4 __attribute__((ext_vector_type(4)));

#define LDA 72    // bf16 row pitch (144 B): 16B-aligned rows

template <int N> struct Int { static constexpr int value = N; };

__device__ __forceinline__ unsigned short f2bf(float f) {
  __bf16 b = (__bf16)f;                      // hardware RTNE v_cvt
  return __builtin_bit_cast(unsigned short, b);
}

__device__ __forceinline__ u16x4 pack4(f32x4 v) {
  u16x4 r;
  r[0] = f2bf(v[0]); r[1] = f2bf(v[1]); r[2] = f2bf(v[2]); r[3] = f2bf(v[3]);
  return r;
}

__device__ __forceinline__ bf16x8 frag8(const unsigned short* p) {
  return __builtin_bit_cast(bf16x8, *reinterpret_cast<const u16x8*>(p));
}

#define MFMA(a, b, c) __builtin_amdgcn_mfma_f32_16x16x32_bf16(a, b, c, 0, 0, 0)

// ---------------------------------------------------------------------------
// In-register C-frag -> A/B-frag conversion (validated permlane butterfly).
// ---------------------------------------------------------------------------
__device__ __forceinline__ void cfrag2bfrag(const f32x4 v[4], bf16x8 out[2]) {
  unsigned O[4][2];
  #pragma unroll
  for (int si = 0; si < 4; ++si) {
    u16x4 p = pack4(v[si]);
    O[si][0] = (unsigned)p[0] | ((unsigned)p[1] << 16);
    O[si][1] = (unsigned)p[2] | ((unsigned)p[3] << 16);
  }
  unsigned H[2][2][2];
  #pragma unroll
  for (int s1 = 0; s1 < 2; ++s1)
    #pragma unroll
    for (int d = 0; d < 2; ++d) {
      auto r = __builtin_amdgcn_permlane32_swap(O[2 * s1][d], O[2 * s1 + 1][d], false, false);
      H[s1][0][d] = r[0];
      H[s1][1][d] = r[1];
    }
  #pragma unroll
  for (int e1 = 0; e1 < 2; ++e1) {
    auto r0 = __builtin_amdgcn_permlane16_swap(H[e1][0][0], H[e1][1][0], false, false);
    auto r1 = __builtin_amdgcn_permlane16_swap(H[e1][0][1], H[e1][1][1], false, false);
    u32x4 f;
    f[0] = r0[0]; f[1] = r1[0]; f[2] = r0[1]; f[3] = r1[1];
    out[e1] = __builtin_bit_cast(bf16x8, f);
  }
}

// ---------------------------------------------------------------------------
// Fuse + pack (unchanged): t=0: M_h = Wq Wk^T * 0.125*log2e; t=1: N_h = Wv Wp_h.
// ---------------------------------------------------------------------------
__global__ __launch_bounds__(256) void fuse_pack(
    const float* __restrict__ Wq, const float* __restrict__ Wk,
    const float* __restrict__ Wv, const float* __restrict__ Wp,
    unsigned short* __restrict__ wf) {
  __shared__ float A[64 * 65];
  __shared__ float B[64 * 65];
  const int blk = blockIdx.x;           // 0..15
  const int t = blk >> 3, h = blk & 7;
  const int tid = threadIdx.x;
  const float* Asrc = (t ? Wv : Wq) + h * 4096;
  const float* Bsrc = (t ? Wp : Wk) + h * 4096;
  for (int i = tid; i < 4096; i += 256) {
    A[(i >> 6) * 65 + (i & 63)] = Asrc[i];
    B[(i >> 6) * 65 + (i & 63)] = Bsrc[i];
  }
  __syncthreads();
  unsigned short* dst = wf + blk * 4096;
  for (int o = 0; o < 16; ++o) {
    int idx = o * 256 + tid;
    int k = idx >> 6, n = idx & 63;
    float s = 0.f;
    if (t == 0) {
      for (int d = 0; d < 64; ++d) s += A[k * 65 + d] * B[n * 65 + d];
      s *= 0.18033688f;                 // 0.125 * log2(e)
    } else {
      for (int d = 0; d < 64; ++d) s += A[k * 65 + d] * B[d * 65 + n];
    }
    int kk = k >> 5, i = k & 7, lg = (k >> 3) & 3, si = n >> 4, l15 = n & 15;
    dst[((kk * 4 + si) * 64 + lg * 16 + l15) * 8 + i] = f2bf(s);
  }
}

// ---------------------------------------------------------------------------
// Main kernel: ONE BATCH PER BLOCK, 4 waves; wave w owns output row-tile
// mt = w (and Z column nt = w). Grid 2048 blocks = 8192 waves = 32 waves/CU
// supply (R19's 4096-wave grid capped occupancy at 30%). Per head per wave:
//   Z = X N (own nt col)   : 8 MFMA -> butterfly -> LDS publish
//   G = M^T X^T (own mt)   : 8 MFMA -> butterfly -> gB
//   S = X G (causal)       : 2(mt+1) MFMA -> in-reg softmax -> pA
//   barrier (Zs[h&1] ready)
//   out += P Z (4 nt)      : 4..8 MFMA (zB from LDS, causal cc-skip)
// 22/24/30/32 MFMA per wave (mt=0..3), Σ=108 — zero duplicated work.
// LDS: 16 KB (staging overlaid with Zs double buffer) -> 10 blocks/CU cap.
// ---------------------------------------------------------------------------
__global__ __launch_bounds__(256, 4) void mha_fwd(
    const float* __restrict__ x, const unsigned short* __restrict__ wf,
    const float* __restrict__ bproj, float* __restrict__ out) {
  __shared__ __attribute__((aligned(16))) unsigned char smem[16384];
  unsigned short* XsBase = reinterpret_cast<unsigned short*>(smem);  // [64*LDA], prologue only
  unsigned short* ZsBase = reinterpret_cast<unsigned short*>(smem);  // [buf][nt][cc][64][8]

  const int tid  = threadIdx.x;
  const int lane = tid & 63;
  const int w    = tid >> 6;         // wave = mt tile = Z's nt column
  const int l15  = lane & 15;
  const int g    = lane >> 4;
  const int kcol = 8 * g;

  // ---- stage this batch (fp32 -> bf16, row-major [s][c]), coalesced ----
  const float* xb = x + (size_t)blockIdx.x * 4096;
  #pragma unroll
  for (int it = 0; it < 4; ++it) {
    int idx = it * 1024 + tid * 4;
    float4 v = *reinterpret_cast<const float4*>(xb + idx);
    f32x4 vv = {v.x, v.y, v.z, v.w};
    *reinterpret_cast<u16x4*>(&XsBase[(idx >> 6) * LDA + (idx & 63)]) = pack4(vv);
  }
  __syncthreads();  // [P1] X staged

  // ---- hoist X into registers (dual-role A/B frags) ----
  bf16x8 xf[2][4];   // element X[t*16+l15][cc*32 + 8g + i]
  #pragma unroll
  for (int cc = 0; cc < 2; ++cc)
    #pragma unroll
    for (int t = 0; t < 4; ++t)
      xf[cc][t] = frag8(&XsBase[(t * 16 + l15) * LDA + cc * 32 + kcol]);
  __syncthreads();  // [P2] X reads done; smem becomes the Zs exchange buffer

  // ---- persistent out C-frags for OUR mt row-tile, bias-init ----
  f32x4 oacc[4];
  #pragma unroll
  for (int nt = 0; nt < 4; ++nt) {
    float bias = bproj[nt * 16 + l15];
    oacc[nt] = f32x4{bias, bias, bias, bias};
  }

  #pragma unroll 1
  for (int h = 0; h < 8; ++h) {
    const unsigned short* mf = wf + h * 4096;          // M^T A-frags
    const unsigned short* nf = wf + 32768 + h * 4096;  // N  B-frags
    unsigned short* zs = ZsBase + (h & 1) * 4096;      // [nt][cc][64][8] u16

    auto head_body = [&](auto MTC) {
      constexpr int MT = decltype(MTC)::value;

      // ---- Z = X N for OWN nt = w; butterfly; publish to LDS ----
      {
        bf16x8 nf0 = frag8(&nf[MT * 512 + lane * 8]);       // nt == w == MT
        bf16x8 nf1 = frag8(&nf[(4 + MT) * 512 + lane * 8]);
        f32x4 zc[4] = {};
        #pragma unroll
        for (int st = 0; st < 4; ++st) {
          zc[st] = MFMA(xf[0][st], nf0, zc[st]);
          zc[st] = MFMA(xf[1][st], nf1, zc[st]);
        }
        bf16x8 zb[2];
        cfrag2bfrag(zc, zb);
        #pragma unroll
        for (int cc = 0; cc < 2; ++cc)
          *reinterpret_cast<u16x8*>(&zs[((MT * 2 + cc) * 64 + lane) * 8]) =
              __builtin_bit_cast(u16x8, zb[cc]);
      }

      // ---- G = M^T X^T (own mt) -> butterfly -> gB ----
      bf16x8 gB[2];
      {
        f32x4 gc[4] = {};
        #pragma unroll
        for (int kk = 0; kk < 2; ++kk)
          #pragma unroll
          for (int ct = 0; ct < 4; ++ct)
            gc[ct] = MFMA(frag8(&mf[(kk * 4 + ct) * 512 + lane * 8]), xf[kk][MT], gc[ct]);
        cfrag2bfrag(gc, gB);
      }

      // ---- S = X G (causal) -> in-reg softmax -> pA ----
      bf16x8 pA[2];
      {
        f32x4 sc[4] = {};
        #pragma unroll
        for (int cc = 0; cc < 2; ++cc)
          #pragma unroll
          for (int st = 0; st < 4; ++st)
            if (st <= MT)
              sc[st] = MFMA(xf[cc][st], gB[cc], sc[st]);

        const int m = MT * 16 + l15;
        float sum = 0.f;
        #pragma unroll
        for (int st = 0; st < 4; ++st) {
          if (st < MT) {
            #pragma unroll
            for (int r = 0; r < 4; ++r) { float e = exp2f(sc[st][r]); sc[st][r] = e; sum += e; }
          } else if (st == MT) {
            #pragma unroll
            for (int r = 0; r < 4; ++r) {
              int s = st * 16 + 4 * g + r;
              float e = (s <= m) ? exp2f(sc[st][r]) : 0.f;
              sc[st][r] = e; sum += e;
            }
          }
        }
        sum += __shfl_xor(sum, 16);
        sum += __shfl_xor(sum, 32);
        float rinv = __builtin_amdgcn_rcpf(sum);
        #pragma unroll
        for (int st = 0; st < 4; ++st)
          if (st <= MT) sc[st] *= rinv;
        cfrag2bfrag(sc, pA);
      }

      __syncthreads();  // [1/head] Zs[h&1] fully published

      // ---- out += P Z : zB from LDS; causal cc-skip ----
      #pragma unroll
      for (int nt = 0; nt < 4; ++nt) {
        bf16x8 zb0 = frag8(&zs[((nt * 2 + 0) * 64 + lane) * 8]);
        oacc[nt] = MFMA(pA[0], zb0, oacc[nt]);
        if (MT >= 2) {
          bf16x8 zb1 = frag8(&zs[((nt * 2 + 1) * 64 + lane) * 8]);
          oacc[nt] = MFMA(pA[1], zb1, oacc[nt]);
        }
      }
    };

    if      (w == 0) head_body(Int<0>{});
    else if (w == 1) head_body(Int<1>{});
    else if (w == 2) head_body(Int<2>{});
    else             head_body(Int<3>{});
  }

  // ---- store fp32 output: our mt tile's 16 rows, all 64 cols ----
  float* ob = out + (size_t)blockIdx.x * 4096;
  #pragma unroll
  for (int r = 0; r < 4; ++r) {
    float* orow = ob + (w * 16 + 4 * g + r) * 64;
    #pragma unroll
    for (int nt = 0; nt < 4; ++nt)
      orow[nt * 16 + l15] = oacc[nt][r];
  }
}

extern "C" void kernel_launch(void* const* d_in, const int* in_sizes, int n_in,
                              void* d_out, int out_size, void* d_ws, size_t ws_size,
                              hipStream_t stream) {
  const float* x  = (const float*)d_in[0];
  const float* Wq = (const float*)d_in[1];
  const float* Wk = (const float*)d_in[2];
  const float* Wv = (const float*)d_in[3];
  const float* Wp = (const float*)d_in[4];
  const float* bp = (const float*)d_in[5];
  unsigned short* wf = (unsigned short*)d_ws;  // 65536 bf16 = 128 KB fused-weight frags

  fuse_pack<<<dim3(16), dim3(256), 0, stream>>>(Wq, Wk, Wv, Wp, wf);
  mha_fwd<<<dim3(2048), dim3(256), 0, stream>>>(x, wf, bp, (float*)d_out);
}